// Round 4
// baseline (23279.338 us; speedup 1.0000x reference)
//
#include <hip/hip_runtime.h>
#include <math.h>

#define B_  256
#define T_  512
#define D_  256
#define H_  1024
#define O_  128
#define K_  (H_ + D_)     // 1280
#define N4H 4096          // 4*H
#define NBLK 256          // persistent grid size (== #CUs)

typedef __attribute__((ext_vector_type(8))) short bf16x8;
typedef __attribute__((ext_vector_type(4))) float f32x4;

__device__ __forceinline__ unsigned short f2bf(float x) {
    union { float f; unsigned u; } v; v.f = x;
    unsigned r = v.u + 0x7fffu + ((v.u >> 16) & 1u);
    return (unsigned short)(r >> 16);
}
__device__ __forceinline__ float bf2f(unsigned short b) {
    union { float f; unsigned u; } v; v.u = ((unsigned)b) << 16;
    return v.f;
}
// round-to-nearest split: x ~= hi + lo, |err| ~ 2^-18 |x|, UNBIASED.
__device__ __forceinline__ void rsplit(float x, unsigned short& hi, unsigned short& lo) {
    unsigned short h = f2bf(x);
    hi = h;
    lo = f2bf(x - bf2f(h));
}

// ---------------------------------------------------------------------------
// Pack weights: rows n' = 4*j + gate (0=g,1=i,2=f,3=o), cols k:
//   k <  H : Wh[gate][j][k] ; k >= H : Wx[gate][j][k-H]. Split hi/lo bf16.
// ---------------------------------------------------------------------------
__global__ __launch_bounds__(256) void pack_weights(
    const float* __restrict__ Wgx, const float* __restrict__ bgx, const float* __restrict__ Wgh,
    const float* __restrict__ Wix, const float* __restrict__ bix, const float* __restrict__ Wih,
    const float* __restrict__ Wfx, const float* __restrict__ bfx, const float* __restrict__ Wfh,
    const float* __restrict__ Wox, const float* __restrict__ box, const float* __restrict__ Woh,
    unsigned short* __restrict__ Whi, unsigned short* __restrict__ Wlo,
    float* __restrict__ biasP)
{
    int idx = blockIdx.x * 256 + threadIdx.x;
    const int total = N4H * K_;
    if (idx < total) {
        int np = idx / K_;
        int k  = idx - np * K_;
        int j = np >> 2, g = np & 3;
        const float* Wh = (g == 0) ? Wgh : (g == 1) ? Wih : (g == 2) ? Wfh : Woh;
        const float* Wx = (g == 0) ? Wgx : (g == 1) ? Wix : (g == 2) ? Wfx : Wox;
        float w = (k < H_) ? Wh[j * H_ + k] : Wx[j * D_ + (k - H_)];
        unsigned short hi = f2bf(w);
        Whi[idx] = hi;
        Wlo[idx] = f2bf(w - bf2f(hi));
    }
    if (idx < N4H) {
        int j = idx >> 2, g = idx & 3;
        const float* bx = (g == 0) ? bgx : (g == 1) ? bix : (g == 2) ? bfx : box;
        biasP[idx] = bx[j];
    }
}

// ---------------------------------------------------------------------------
// Persistent LSTM with a HAND-ROLLED grid barrier (no cooperative API —
// hipLaunchCooperativeKernel silently failed to launch in rounds 2/3).
// 256 blocks (cg=blk&63, rg=blk>>6), 256 threads (4 waves), 1 block/CU by
// __launch_bounds__(256,1) -> all blocks co-resident by construction.
// Each wave keeps its K-slice of the 64-col W tile (hi+lo) in 320 VGPRs,
// loaded ONCE. c-state in registers. h ping-pongs in global memory.
// ---------------------------------------------------------------------------
__global__ __launch_bounds__(256, 1) void lstm_persistent(
    const float* __restrict__ x,
    const unsigned short* __restrict__ Whi, const unsigned short* __restrict__ Wlo,
    const float* __restrict__ biasP,
    unsigned short* __restrict__ hA_hi, unsigned short* __restrict__ hA_lo,
    unsigned short* __restrict__ hB_hi, unsigned short* __restrict__ hB_lo,
    unsigned int* __restrict__ bar)
{
    __shared__ float zbuf[4][64][68];   // [wave][col][row+pad]

    const int tid  = threadIdx.x;
    const int wave = tid >> 6;
    const int lane = tid & 63;
    const int lrow = lane & 15;
    const int quad = lane >> 4;

    const int cg = blockIdx.x & 63;
    const int rg = blockIdx.x >> 6;
    const int rbase = rg * 64;
    const int cbase = cg * 64;

    // ---- load W fragments into registers (once) ----
    // wf[i][cs][p]: i<8 -> h chunk (k = 256*wave + 32*i), i>=8 -> x chunk
    bf16x8 wf[10][4][2];
    #pragma unroll
    for (int i = 0; i < 8; ++i) {
        int k = wave * 256 + i * 32;
        #pragma unroll
        for (int cs = 0; cs < 4; ++cs) {
            size_t off = (size_t)(cbase + cs * 16 + lrow) * K_ + k + quad * 8;
            wf[i][cs][0] = *(const bf16x8*)(Whi + off);
            wf[i][cs][1] = *(const bf16x8*)(Wlo + off);
        }
    }
    #pragma unroll
    for (int i = 0; i < 2; ++i) {
        int k = 1024 + wave * 64 + i * 32;
        #pragma unroll
        for (int cs = 0; cs < 4; ++cs) {
            size_t off = (size_t)(cbase + cs * 16 + lrow) * K_ + k + quad * 8;
            wf[8 + i][cs][0] = *(const bf16x8*)(Whi + off);
            wf[8 + i][cs][1] = *(const bf16x8*)(Wlo + off);
        }
    }

    // ---- per-thread cell state (4 cells of one row), in registers ----
    const int b_loc = tid >> 2;          // 0..63
    const int cq    = tid & 3;
    const int brow  = rbase + b_loc;
    const int jg0   = cg * 16 + cq * 4;  // first owned LSTM cell
    float creg[4] = {0.f, 0.f, 0.f, 0.f};

    for (int t = 0; t < T_; ++t) {
        const unsigned short* ih_hi = (t & 1) ? hB_hi : hA_hi;
        const unsigned short* ih_lo = (t & 1) ? hB_lo : hA_lo;
        unsigned short* oh_hi = (t & 1) ? hA_hi : hB_hi;
        unsigned short* oh_lo = (t & 1) ? hA_lo : hB_lo;

        f32x4 acc[4][4];
        #pragma unroll
        for (int rs = 0; rs < 4; ++rs)
            #pragma unroll
            for (int cs = 0; cs < 4; ++cs)
                acc[rs][cs] = (f32x4){0.f, 0.f, 0.f, 0.f};

        // ---- recurrent part: 8 chunks of 32 from h ----
        #pragma unroll
        for (int i = 0; i < 8; ++i) {
            const int kc = wave * 256 + i * 32;
            bf16x8 Ah[4], Al[4];
            #pragma unroll
            for (int rs = 0; rs < 4; ++rs) {
                size_t off = (size_t)(rbase + rs * 16 + lrow) * H_ + kc + quad * 8;
                Ah[rs] = *(const bf16x8*)(ih_hi + off);
                Al[rs] = *(const bf16x8*)(ih_lo + off);
            }
            #pragma unroll
            for (int rs = 0; rs < 4; ++rs)
                #pragma unroll
                for (int cs = 0; cs < 4; ++cs) {
                    acc[rs][cs] = __builtin_amdgcn_mfma_f32_16x16x32_bf16(Ah[rs], wf[i][cs][0], acc[rs][cs], 0, 0, 0);
                    acc[rs][cs] = __builtin_amdgcn_mfma_f32_16x16x32_bf16(Ah[rs], wf[i][cs][1], acc[rs][cs], 0, 0, 0);
                    acc[rs][cs] = __builtin_amdgcn_mfma_f32_16x16x32_bf16(Al[rs], wf[i][cs][0], acc[rs][cs], 0, 0, 0);
                }
        }

        // ---- input part: 2 chunks of 32 from x_t (fp32, split on the fly) ----
        #pragma unroll
        for (int i = 0; i < 2; ++i) {
            const int kx = wave * 64 + i * 32;   // column within x row slice
            bf16x8 Ah[4], Al[4];
            #pragma unroll
            for (int rs = 0; rs < 4; ++rs) {
                const float* p = x + (size_t)(rbase + rs * 16 + lrow) * (T_ * D_)
                                   + (size_t)t * D_ + kx + quad * 8;
                float4 v0 = *(const float4*)p;
                float4 v1 = *(const float4*)(p + 4);
                float vv[8] = {v0.x, v0.y, v0.z, v0.w, v1.x, v1.y, v1.z, v1.w};
                bf16x8 h8, l8;
                #pragma unroll
                for (int j = 0; j < 8; ++j) {
                    unsigned short hh, ll;
                    rsplit(vv[j], hh, ll);
                    h8[j] = (short)hh; l8[j] = (short)ll;
                }
                Ah[rs] = h8; Al[rs] = l8;
            }
            #pragma unroll
            for (int rs = 0; rs < 4; ++rs)
                #pragma unroll
                for (int cs = 0; cs < 4; ++cs) {
                    acc[rs][cs] = __builtin_amdgcn_mfma_f32_16x16x32_bf16(Ah[rs], wf[8 + i][cs][0], acc[rs][cs], 0, 0, 0);
                    acc[rs][cs] = __builtin_amdgcn_mfma_f32_16x16x32_bf16(Ah[rs], wf[8 + i][cs][1], acc[rs][cs], 0, 0, 0);
                    acc[rs][cs] = __builtin_amdgcn_mfma_f32_16x16x32_bf16(Al[rs], wf[8 + i][cs][0], acc[rs][cs], 0, 0, 0);
                }
        }

        // ---- per-wave partials -> LDS (b128 stores, C-layout aware) ----
        #pragma unroll
        for (int rs = 0; rs < 4; ++rs)
            #pragma unroll
            for (int cs = 0; cs < 4; ++cs) {
                float4 v = {acc[rs][cs][0], acc[rs][cs][1], acc[rs][cs][2], acc[rs][cs][3]};
                *(float4*)&zbuf[wave][cs * 16 + lrow][rs * 16 + quad * 4] = v;
            }
        __syncthreads();

        // ---- epilogue: 4 cells per thread; c in registers ----
        float zz[16];
        #pragma unroll
        for (int i = 0; i < 16; ++i) {
            float s = 0.f;
            #pragma unroll
            for (int w = 0; w < 4; ++w)
                s += zbuf[w][cq * 16 + i][b_loc];
            zz[i] = s;
        }

        const float* bp = biasP + cbase + cq * 16;
        unsigned short hh4[4], hl4[4];
        #pragma unroll
        for (int j = 0; j < 4; ++j) {
            float zg = zz[4 * j + 0] + bp[4 * j + 0];
            float zi = zz[4 * j + 1] + bp[4 * j + 1];
            float zf = zz[4 * j + 2] + bp[4 * j + 2];
            float zo = zz[4 * j + 3] + bp[4 * j + 3];
            float g  = tanhf(zg);
            float ig = 1.f / (1.f + expf(-zi));
            float fg = 1.f / (1.f + expf(-zf));
            float og = 1.f / (1.f + expf(-zo));
            float cn = g * ig + creg[j] * fg;
            float hn = tanhf(cn) * og;
            creg[j] = cn;
            rsplit(hn, hh4[j], hl4[j]);
        }
        *(ushort4*)&oh_hi[(size_t)brow * H_ + jg0] = make_ushort4(hh4[0], hh4[1], hh4[2], hh4[3]);
        *(ushort4*)&oh_lo[(size_t)brow * H_ + jg0] = make_ushort4(hl4[0], hl4[1], hl4[2], hl4[3]);

        // ---- hand-rolled grid barrier (monotone counter, sense-free) ----
        __syncthreads();                       // all block stores issued+drained
        if (tid == 0) {
            __threadfence();                   // release: flush to device scope
            atomicAdd(bar, 1u);
            const unsigned target = (unsigned)NBLK * (unsigned)(t + 1);
            while (__hip_atomic_load(bar, __ATOMIC_RELAXED, __HIP_MEMORY_SCOPE_AGENT) < target)
                __builtin_amdgcn_s_sleep(2);
            __threadfence();                   // acquire: invalidate L1/L2
        }
        __syncthreads();
    }
}

// ---------------------------------------------------------------------------
// Final projection + softmax: one block per batch row, 128 threads.
// ---------------------------------------------------------------------------
__global__ __launch_bounds__(128) void final_proj(
    const unsigned short* __restrict__ hhi, const unsigned short* __restrict__ hlo,
    const float* __restrict__ Why, const float* __restrict__ bhy,
    float* __restrict__ out)
{
    __shared__ float hsh[H_];
    __shared__ float red[O_];
    const int b = blockIdx.x, tid = threadIdx.x;

    for (int k = tid; k < H_; k += O_)
        hsh[k] = bf2f(hhi[(size_t)b * H_ + k]) + bf2f(hlo[(size_t)b * H_ + k]);
    __syncthreads();

    float s = bhy[tid];
    const float* w = Why + (size_t)tid * H_;
    #pragma unroll 4
    for (int k = 0; k < H_; k += 4) {
        float4 wv = *(const float4*)(w + k);
        s += hsh[k] * wv.x + hsh[k + 1] * wv.y + hsh[k + 2] * wv.z + hsh[k + 3] * wv.w;
    }

    red[tid] = s; __syncthreads();
    for (int off = 64; off > 0; off >>= 1) {
        if (tid < off) red[tid] = fmaxf(red[tid], red[tid + off]);
        __syncthreads();
    }
    float mx = red[0]; __syncthreads();
    float e = expf(s - mx);
    red[tid] = e; __syncthreads();
    for (int off = 64; off > 0; off >>= 1) {
        if (tid < off) red[tid] += red[tid + off];
        __syncthreads();
    }
    out[(size_t)b * O_ + tid] = e / red[0];
}

// ---------------------------------------------------------------------------
extern "C" void kernel_launch(void* const* d_in, const int* in_sizes, int n_in,
                              void* d_out, int out_size, void* d_ws, size_t ws_size,
                              hipStream_t stream)
{
    const float* x   = (const float*)d_in[0];
    const float* Wgx = (const float*)d_in[1];
    const float* bgx = (const float*)d_in[2];
    const float* Wgh = (const float*)d_in[3];
    const float* Wix = (const float*)d_in[4];
    const float* bix = (const float*)d_in[5];
    const float* Wih = (const float*)d_in[6];
    const float* Wfx = (const float*)d_in[7];
    const float* bfx = (const float*)d_in[8];
    const float* Wfh = (const float*)d_in[9];
    const float* Wox = (const float*)d_in[10];
    const float* box = (const float*)d_in[11];
    const float* Woh = (const float*)d_in[12];
    const float* Why = (const float*)d_in[13];
    const float* bhy = (const float*)d_in[14];

    // workspace layout (~23 MB)
    unsigned short* Whi   = (unsigned short*)d_ws;
    unsigned short* Wlo   = Whi + (size_t)N4H * K_;
    float*          bP    = (float*)(Wlo + (size_t)N4H * K_);
    unsigned short* hA_hi = (unsigned short*)(bP + N4H);
    unsigned short* hA_lo = hA_hi + (size_t)B_ * H_;
    unsigned short* hB_hi = hA_lo + (size_t)B_ * H_;
    unsigned short* hB_lo = hB_hi + (size_t)B_ * H_;
    unsigned int*   bar   = (unsigned int*)(hB_lo + (size_t)B_ * H_);

    // zero the t=0 read buffer (hA_hi + hA_lo are contiguous) and the barrier
    hipMemsetAsync(hA_hi, 0, (size_t)B_ * H_ * 4, stream);
    hipMemsetAsync(bar, 0, sizeof(unsigned int), stream);

    const int totalW = N4H * K_;
    pack_weights<<<(totalW + 255) / 256, 256, 0, stream>>>(
        Wgx, bgx, Wgh, Wix, bix, Wih, Wfx, bfx, Wfh, Wox, box, Woh,
        Whi, Wlo, bP);

    lstm_persistent<<<NBLK, 256, 0, stream>>>(
        x, Whi, Wlo, bP, hA_hi, hA_lo, hB_hi, hB_lo, bar);

    // t=511 (odd) wrote the A buffers
    final_proj<<<B_, 128, 0, stream>>>(hA_hi, hA_lo, Why, bhy, (float*)d_out);
}

// Round 5
// 20456.847 us; speedup vs baseline: 1.1380x; 1.1380x over previous
//
#include <hip/hip_runtime.h>
#include <math.h>

#define B_  256
#define T_  512
#define D_  256
#define H_  1024
#define O_  128
#define K_  (H_ + D_)     // 1280
#define N4H 4096          // 4*H
#define NBLK 256          // persistent grid size (== #CUs)

typedef __attribute__((ext_vector_type(8))) short bf16x8;
typedef __attribute__((ext_vector_type(4))) float f32x4;

__device__ __forceinline__ unsigned short f2bf(float x) {
    union { float f; unsigned u; } v; v.f = x;
    unsigned r = v.u + 0x7fffu + ((v.u >> 16) & 1u);
    return (unsigned short)(r >> 16);
}
__device__ __forceinline__ float bf2f(unsigned short b) {
    union { float f; unsigned u; } v; v.u = ((unsigned)b) << 16;
    return v.f;
}
// round-to-nearest split: x ~= hi + lo, |err| ~ 2^-18 |x|, UNBIASED.
__device__ __forceinline__ void rsplit(float x, unsigned short& hi, unsigned short& lo) {
    unsigned short h = f2bf(x);
    hi = h;
    lo = f2bf(x - bf2f(h));
}

// ---------------------------------------------------------------------------
// Pack weights: rows n' = 4*j + gate (0=g,1=i,2=f,3=o), cols k:
//   k <  H : Wh[gate][j][k] ; k >= H : Wx[gate][j][k-H]. Split hi/lo bf16.
// ---------------------------------------------------------------------------
__global__ __launch_bounds__(256) void pack_weights(
    const float* __restrict__ Wgx, const float* __restrict__ bgx, const float* __restrict__ Wgh,
    const float* __restrict__ Wix, const float* __restrict__ bix, const float* __restrict__ Wih,
    const float* __restrict__ Wfx, const float* __restrict__ bfx, const float* __restrict__ Wfh,
    const float* __restrict__ Wox, const float* __restrict__ box, const float* __restrict__ Woh,
    unsigned short* __restrict__ Whi, unsigned short* __restrict__ Wlo,
    float* __restrict__ biasP)
{
    int idx = blockIdx.x * 256 + threadIdx.x;
    const int total = N4H * K_;
    if (idx < total) {
        int np = idx / K_;
        int k  = idx - np * K_;
        int j = np >> 2, g = np & 3;
        const float* Wh = (g == 0) ? Wgh : (g == 1) ? Wih : (g == 2) ? Wfh : Woh;
        const float* Wx = (g == 0) ? Wgx : (g == 1) ? Wix : (g == 2) ? Wfx : Wox;
        float w = (k < H_) ? Wh[j * H_ + k] : Wx[j * D_ + (k - H_)];
        unsigned short hi = f2bf(w);
        Whi[idx] = hi;
        Wlo[idx] = f2bf(w - bf2f(hi));
    }
    if (idx < N4H) {
        int j = idx >> 2, g = idx & 3;
        const float* bx = (g == 0) ? bgx : (g == 1) ? bix : (g == 2) ? bfx : box;
        biasP[idx] = bx[j];
    }
}

// ---------------------------------------------------------------------------
// Persistent LSTM, W streamed from XCD-local L2 (R4 showed W-in-VGPR is
// impossible at the 256 arch-VGPR cap; compiler rematerializes). 256 blocks,
// 512 threads (8 waves -> 2 waves/SIMD for latency hiding), 1 block/CU.
// XCD swizzle: xcd=blk&7 owns cols [xcd*512, xcd*512+512) -> 2.6 MB W slice
// resident in its 4 MB L2. Waves split K 8x160 (4 h-chunks + 1 x-chunk).
// c-state in registers; h ping-pongs in global; hand-rolled grid barrier.
// ---------------------------------------------------------------------------
__global__ __launch_bounds__(512, 2) void lstm_persistent(
    const float* __restrict__ x,
    const unsigned short* __restrict__ Whi, const unsigned short* __restrict__ Wlo,
    const float* __restrict__ biasP,
    unsigned short* __restrict__ hA_hi, unsigned short* __restrict__ hA_lo,
    unsigned short* __restrict__ hB_hi, unsigned short* __restrict__ hB_lo,
    unsigned int* __restrict__ bar)
{
    __shared__ float zbuf[8][64][68];   // [wave][row][col+pad], 139 KB

    const int tid  = threadIdx.x;
    const int wave = tid >> 6;          // 0..7
    const int lane = tid & 63;
    const int lrow = lane & 15;
    const int quad = lane >> 4;

    // XCD-aware mapping: blocks round-robin XCDs by blockIdx; concentrate
    // each XCD's blocks on 8 consecutive column groups (512 cols, 2.6 MB W).
    const int xcd = blockIdx.x & 7;
    const int idx = blockIdx.x >> 3;     // 0..31
    const int cg  = xcd * 8 + (idx & 7); // 0..63
    const int rg  = idx >> 3;            // 0..3
    const int rbase = rg * 64;
    const int cbase = cg * 64;

    // ---- per-thread cell state (2 cells of one row), in registers ----
    const int b_loc = tid >> 3;          // 0..63
    const int ce    = tid & 7;           // col eighth (8 gate-cols = 2 cells)
    const int brow  = rbase + b_loc;
    const int jg0   = cg * 16 + ce * 2;  // first owned LSTM cell
    float creg[2] = {0.f, 0.f};

    // bias for the 8 gate-cols this thread owns (hoisted out of t-loop)
    float bias[8];
    #pragma unroll
    for (int i = 0; i < 8; ++i) bias[i] = biasP[cbase + ce * 8 + i];

    for (int t = 0; t < T_; ++t) {
        const unsigned short* ih_hi = (t & 1) ? hB_hi : hA_hi;
        const unsigned short* ih_lo = (t & 1) ? hB_lo : hA_lo;
        unsigned short* oh_hi = (t & 1) ? hA_hi : hB_hi;
        unsigned short* oh_lo = (t & 1) ? hA_lo : hB_lo;

        f32x4 acc[4][4];
        #pragma unroll
        for (int rs = 0; rs < 4; ++rs)
            #pragma unroll
            for (int cs = 0; cs < 4; ++cs)
                acc[rs][cs] = (f32x4){0.f, 0.f, 0.f, 0.f};

        // ---- recurrent part: 4 chunks of 32 from h (K = wave*128 + i*32) ----
        #pragma unroll
        for (int i = 0; i < 4; ++i) {
            const int kc = wave * 128 + i * 32;
            bf16x8 Ah[4], Al[4], Bh[4], Bl[4];
            #pragma unroll
            for (int rs = 0; rs < 4; ++rs) {
                size_t off = (size_t)(rbase + rs * 16 + lrow) * H_ + kc + quad * 8;
                Ah[rs] = *(const bf16x8*)(ih_hi + off);
                Al[rs] = *(const bf16x8*)(ih_lo + off);
            }
            #pragma unroll
            for (int cs = 0; cs < 4; ++cs) {
                size_t off = (size_t)(cbase + cs * 16 + lrow) * K_ + kc + quad * 8;
                Bh[cs] = *(const bf16x8*)(Whi + off);
                Bl[cs] = *(const bf16x8*)(Wlo + off);
            }
            #pragma unroll
            for (int rs = 0; rs < 4; ++rs)
                #pragma unroll
                for (int cs = 0; cs < 4; ++cs) {
                    acc[rs][cs] = __builtin_amdgcn_mfma_f32_16x16x32_bf16(Ah[rs], Bh[cs], acc[rs][cs], 0, 0, 0);
                    acc[rs][cs] = __builtin_amdgcn_mfma_f32_16x16x32_bf16(Ah[rs], Bl[cs], acc[rs][cs], 0, 0, 0);
                    acc[rs][cs] = __builtin_amdgcn_mfma_f32_16x16x32_bf16(Al[rs], Bh[cs], acc[rs][cs], 0, 0, 0);
                }
        }

        // ---- input part: 1 chunk of 32 from x_t (fp32, split on the fly) ----
        {
            const int kx = wave * 32;            // column within x row slice
            const int kg = 1024 + kx;            // packed-K coordinate
            bf16x8 Ah[4], Al[4], Bh[4], Bl[4];
            #pragma unroll
            for (int rs = 0; rs < 4; ++rs) {
                const float* p = x + (size_t)(rbase + rs * 16 + lrow) * (T_ * D_)
                                   + (size_t)t * D_ + kx + quad * 8;
                float4 v0 = *(const float4*)p;
                float4 v1 = *(const float4*)(p + 4);
                float vv[8] = {v0.x, v0.y, v0.z, v0.w, v1.x, v1.y, v1.z, v1.w};
                bf16x8 h8, l8;
                #pragma unroll
                for (int j = 0; j < 8; ++j) {
                    unsigned short hh, ll;
                    rsplit(vv[j], hh, ll);
                    h8[j] = (short)hh; l8[j] = (short)ll;
                }
                Ah[rs] = h8; Al[rs] = l8;
            }
            #pragma unroll
            for (int cs = 0; cs < 4; ++cs) {
                size_t off = (size_t)(cbase + cs * 16 + lrow) * K_ + kg + quad * 8;
                Bh[cs] = *(const bf16x8*)(Whi + off);
                Bl[cs] = *(const bf16x8*)(Wlo + off);
            }
            #pragma unroll
            for (int rs = 0; rs < 4; ++rs)
                #pragma unroll
                for (int cs = 0; cs < 4; ++cs) {
                    acc[rs][cs] = __builtin_amdgcn_mfma_f32_16x16x32_bf16(Ah[rs], Bh[cs], acc[rs][cs], 0, 0, 0);
                    acc[rs][cs] = __builtin_amdgcn_mfma_f32_16x16x32_bf16(Ah[rs], Bl[cs], acc[rs][cs], 0, 0, 0);
                    acc[rs][cs] = __builtin_amdgcn_mfma_f32_16x16x32_bf16(Al[rs], Bh[cs], acc[rs][cs], 0, 0, 0);
                }
        }

        // ---- per-wave partials -> LDS, [row][col] scalar (2-way max = free) ----
        #pragma unroll
        for (int rs = 0; rs < 4; ++rs)
            #pragma unroll
            for (int cs = 0; cs < 4; ++cs)
                #pragma unroll
                for (int r = 0; r < 4; ++r)
                    zbuf[wave][rs * 16 + quad * 4 + r][cs * 16 + lrow] = acc[rs][cs][r];
        __syncthreads();

        // ---- epilogue: 2 cells per thread; float4 reduce over 8 waves ----
        float zz[8];
        #pragma unroll
        for (int q = 0; q < 2; ++q) {
            float sx = 0.f, sy = 0.f, sz = 0.f, sw = 0.f;
            #pragma unroll
            for (int w = 0; w < 8; ++w) {
                float4 v = *(const float4*)&zbuf[w][b_loc][ce * 8 + q * 4];
                sx += v.x; sy += v.y; sz += v.z; sw += v.w;
            }
            zz[q * 4 + 0] = sx; zz[q * 4 + 1] = sy;
            zz[q * 4 + 2] = sz; zz[q * 4 + 3] = sw;
        }

        unsigned short hh2[2], hl2[2];
        #pragma unroll
        for (int j = 0; j < 2; ++j) {
            float zg = zz[4 * j + 0] + bias[4 * j + 0];
            float zi = zz[4 * j + 1] + bias[4 * j + 1];
            float zf = zz[4 * j + 2] + bias[4 * j + 2];
            float zo = zz[4 * j + 3] + bias[4 * j + 3];
            float g  = tanhf(zg);
            float ig = 1.f / (1.f + expf(-zi));
            float fg = 1.f / (1.f + expf(-zf));
            float og = 1.f / (1.f + expf(-zo));
            float cn = g * ig + creg[j] * fg;
            float hn = tanhf(cn) * og;
            creg[j] = cn;
            rsplit(hn, hh2[j], hl2[j]);
        }
        *(ushort2*)&oh_hi[(size_t)brow * H_ + jg0] = make_ushort2(hh2[0], hh2[1]);
        *(ushort2*)&oh_lo[(size_t)brow * H_ + jg0] = make_ushort2(hl2[0], hl2[1]);

        // ---- hand-rolled grid barrier (monotone counter) ----
        __syncthreads();
        if (tid == 0) {
            __threadfence();                   // release to device scope
            atomicAdd(bar, 1u);
            const unsigned target = (unsigned)NBLK * (unsigned)(t + 1);
            while (__hip_atomic_load(bar, __ATOMIC_RELAXED, __HIP_MEMORY_SCOPE_AGENT) < target)
                __builtin_amdgcn_s_sleep(2);
            __threadfence();                   // acquire
        }
        __syncthreads();
    }
}

// ---------------------------------------------------------------------------
// Final projection + softmax: one block per batch row, 128 threads.
// ---------------------------------------------------------------------------
__global__ __launch_bounds__(128) void final_proj(
    const unsigned short* __restrict__ hhi, const unsigned short* __restrict__ hlo,
    const float* __restrict__ Why, const float* __restrict__ bhy,
    float* __restrict__ out)
{
    __shared__ float hsh[H_];
    __shared__ float red[O_];
    const int b = blockIdx.x, tid = threadIdx.x;

    for (int k = tid; k < H_; k += O_)
        hsh[k] = bf2f(hhi[(size_t)b * H_ + k]) + bf2f(hlo[(size_t)b * H_ + k]);
    __syncthreads();

    float s = bhy[tid];
    const float* w = Why + (size_t)tid * H_;
    #pragma unroll 4
    for (int k = 0; k < H_; k += 4) {
        float4 wv = *(const float4*)(w + k);
        s += hsh[k] * wv.x + hsh[k + 1] * wv.y + hsh[k + 2] * wv.z + hsh[k + 3] * wv.w;
    }

    red[tid] = s; __syncthreads();
    for (int off = 64; off > 0; off >>= 1) {
        if (tid < off) red[tid] = fmaxf(red[tid], red[tid + off]);
        __syncthreads();
    }
    float mx = red[0]; __syncthreads();
    float e = expf(s - mx);
    red[tid] = e; __syncthreads();
    for (int off = 64; off > 0; off >>= 1) {
        if (tid < off) red[tid] += red[tid + off];
        __syncthreads();
    }
    out[(size_t)b * O_ + tid] = e / red[0];
}

// ---------------------------------------------------------------------------
extern "C" void kernel_launch(void* const* d_in, const int* in_sizes, int n_in,
                              void* d_out, int out_size, void* d_ws, size_t ws_size,
                              hipStream_t stream)
{
    const float* x   = (const float*)d_in[0];
    const float* Wgx = (const float*)d_in[1];
    const float* bgx = (const float*)d_in[2];
    const float* Wgh = (const float*)d_in[3];
    const float* Wix = (const float*)d_in[4];
    const float* bix = (const float*)d_in[5];
    const float* Wih = (const float*)d_in[6];
    const float* Wfx = (const float*)d_in[7];
    const float* bfx = (const float*)d_in[8];
    const float* Wfh = (const float*)d_in[9];
    const float* Wox = (const float*)d_in[10];
    const float* box = (const float*)d_in[11];
    const float* Woh = (const float*)d_in[12];
    const float* Why = (const float*)d_in[13];
    const float* bhy = (const float*)d_in[14];

    // workspace layout (~23 MB)
    unsigned short* Whi   = (unsigned short*)d_ws;
    unsigned short* Wlo   = Whi + (size_t)N4H * K_;
    float*          bP    = (float*)(Wlo + (size_t)N4H * K_);
    unsigned short* hA_hi = (unsigned short*)(bP + N4H);
    unsigned short* hA_lo = hA_hi + (size_t)B_ * H_;
    unsigned short* hB_hi = hA_lo + (size_t)B_ * H_;
    unsigned short* hB_lo = hB_hi + (size_t)B_ * H_;
    unsigned int*   bar   = (unsigned int*)(hB_lo + (size_t)B_ * H_);

    // zero the t=0 read buffer (hA_hi + hA_lo are contiguous) and the barrier
    hipMemsetAsync(hA_hi, 0, (size_t)B_ * H_ * 4, stream);
    hipMemsetAsync(bar, 0, sizeof(unsigned int), stream);

    const int totalW = N4H * K_;
    pack_weights<<<(totalW + 255) / 256, 256, 0, stream>>>(
        Wgx, bgx, Wgh, Wix, bix, Wih, Wfx, bfx, Wfh, Wox, box, Woh,
        Whi, Wlo, bP);

    lstm_persistent<<<NBLK, 512, 0, stream>>>(
        x, Whi, Wlo, bP, hA_hi, hA_lo, hB_hi, hB_lo, bar);

    // t=511 (odd) wrote the A buffers
    final_proj<<<B_, 128, 0, stream>>>(hA_hi, hA_lo, Why, bhy, (float*)d_out);
}

// Round 6
// 15881.981 us; speedup vs baseline: 1.4658x; 1.2881x over previous
//
#include <hip/hip_runtime.h>
#include <math.h>

#define B_  256
#define T_  512
#define D_  256
#define H_  1024
#define O_  128
#define K_  (H_ + D_)     // 1280
#define N4H 4096          // 4*H
#define NBLK 256          // persistent grid size (== #CUs)

typedef __attribute__((ext_vector_type(8))) short bf16x8;
typedef __attribute__((ext_vector_type(4))) float f32x4;

__device__ __forceinline__ unsigned short f2bf(float x) {
    union { float f; unsigned u; } v; v.f = x;
    unsigned r = v.u + 0x7fffu + ((v.u >> 16) & 1u);
    return (unsigned short)(r >> 16);
}
__device__ __forceinline__ float bf2f(unsigned short b) {
    union { float f; unsigned u; } v; v.u = ((unsigned)b) << 16;
    return v.f;
}
// round-to-nearest split: x ~= hi + lo, |err| ~ 2^-18 |x|, UNBIASED.
__device__ __forceinline__ void rsplit(float x, unsigned short& hi, unsigned short& lo) {
    unsigned short h = f2bf(x);
    hi = h;
    lo = f2bf(x - bf2f(h));
}

// Coherent (agent-scope) 16B h-load as 2x8B relaxed atomics — reads the
// device coherent point, bypassing the (possibly stale) per-XCD L2 without
// any cache-invalidating fence. Offsets are 16B-aligned by construction.
__device__ __forceinline__ bf16x8 load_h16(const unsigned short* p) {
    union { unsigned long long q[2]; bf16x8 v; } u;
    u.q[0] = __hip_atomic_load((const unsigned long long*)p,
                               __ATOMIC_RELAXED, __HIP_MEMORY_SCOPE_AGENT);
    u.q[1] = __hip_atomic_load((const unsigned long long*)(p + 4),
                               __ATOMIC_RELAXED, __HIP_MEMORY_SCOPE_AGENT);
    return u.v;
}
// Coherent 4B h-store (2 bf16), relaxed agent scope.
__device__ __forceinline__ void store_h4(unsigned short* p, unsigned short a, unsigned short b) {
    unsigned int v = (unsigned int)a | ((unsigned int)b << 16);
    __hip_atomic_store((unsigned int*)p, v,
                       __ATOMIC_RELAXED, __HIP_MEMORY_SCOPE_AGENT);
}

// ---------------------------------------------------------------------------
// Pack weights: rows n' = 4*j + gate (0=g,1=i,2=f,3=o), cols k:
//   k <  H : Wh[gate][j][k] ; k >= H : Wx[gate][j][k-H]. Split hi/lo bf16.
// ---------------------------------------------------------------------------
__global__ __launch_bounds__(256) void pack_weights(
    const float* __restrict__ Wgx, const float* __restrict__ bgx, const float* __restrict__ Wgh,
    const float* __restrict__ Wix, const float* __restrict__ bix, const float* __restrict__ Wih,
    const float* __restrict__ Wfx, const float* __restrict__ bfx, const float* __restrict__ Wfh,
    const float* __restrict__ Wox, const float* __restrict__ box, const float* __restrict__ Woh,
    unsigned short* __restrict__ Whi, unsigned short* __restrict__ Wlo,
    float* __restrict__ biasP)
{
    int idx = blockIdx.x * 256 + threadIdx.x;
    const int total = N4H * K_;
    if (idx < total) {
        int np = idx / K_;
        int k  = idx - np * K_;
        int j = np >> 2, g = np & 3;
        const float* Wh = (g == 0) ? Wgh : (g == 1) ? Wih : (g == 2) ? Wfh : Woh;
        const float* Wx = (g == 0) ? Wgx : (g == 1) ? Wix : (g == 2) ? Wfx : Wox;
        float w = (k < H_) ? Wh[j * H_ + k] : Wx[j * D_ + (k - H_)];
        unsigned short hi = f2bf(w);
        Whi[idx] = hi;
        Wlo[idx] = f2bf(w - bf2f(hi));
    }
    if (idx < N4H) {
        int j = idx >> 2, g = idx & 3;
        const float* bx = (g == 0) ? bgx : (g == 1) ? bix : (g == 2) ? bfx : box;
        biasP[idx] = bx[j];
    }
}

// ---------------------------------------------------------------------------
// Persistent LSTM. R5 lesson: the grid barrier's acquire __threadfence()
// invalidated the per-XCD L2 every step, evicting the W slice -> 18.6 MB/step
// HBM refetch at latency-limited BW. R6: h moves through relaxed AGENT-scope
// atomics (coherent point, no cache flush); W/x use normal cached loads and
// stay L2-resident; barrier uses release-RMW (writeback only, NO invalidate).
// 256 blocks, 512 threads (8 waves, 2/SIMD), XCD swizzle: xcd=blk&7 owns
// cols [xcd*512, +512) -> 2.6 MB W slice resident in its 4 MB L2.
// ---------------------------------------------------------------------------
__global__ __launch_bounds__(512, 2) void lstm_persistent(
    const float* __restrict__ x,
    const unsigned short* __restrict__ Whi, const unsigned short* __restrict__ Wlo,
    const float* __restrict__ biasP,
    unsigned short* __restrict__ hA_hi, unsigned short* __restrict__ hA_lo,
    unsigned short* __restrict__ hB_hi, unsigned short* __restrict__ hB_lo,
    unsigned int* __restrict__ bar)
{
    __shared__ float zbuf[8][64][68];   // [wave][row][col+pad], 139 KB

    const int tid  = threadIdx.x;
    const int wave = tid >> 6;          // 0..7
    const int lane = tid & 63;
    const int lrow = lane & 15;
    const int quad = lane >> 4;

    const int xcd = blockIdx.x & 7;
    const int idx = blockIdx.x >> 3;     // 0..31
    const int cg  = xcd * 8 + (idx & 7); // 0..63
    const int rg  = idx >> 3;            // 0..3
    const int rbase = rg * 64;
    const int cbase = cg * 64;

    const int b_loc = tid >> 3;          // 0..63
    const int ce    = tid & 7;           // col eighth (8 gate-cols = 2 cells)
    const int brow  = rbase + b_loc;
    const int jg0   = cg * 16 + ce * 2;  // first owned LSTM cell
    float creg[2] = {0.f, 0.f};

    float bias[8];
    #pragma unroll
    for (int i = 0; i < 8; ++i) bias[i] = biasP[cbase + ce * 8 + i];

    for (int t = 0; t < T_; ++t) {
        const unsigned short* ih_hi = (t & 1) ? hB_hi : hA_hi;
        const unsigned short* ih_lo = (t & 1) ? hB_lo : hA_lo;
        unsigned short* oh_hi = (t & 1) ? hA_hi : hB_hi;
        unsigned short* oh_lo = (t & 1) ? hA_lo : hB_lo;

        f32x4 acc[4][4];
        #pragma unroll
        for (int rs = 0; rs < 4; ++rs)
            #pragma unroll
            for (int cs = 0; cs < 4; ++cs)
                acc[rs][cs] = (f32x4){0.f, 0.f, 0.f, 0.f};

        // ---- recurrent part: 4 chunks of 32 from h (K = wave*128 + i*32) ----
        #pragma unroll
        for (int i = 0; i < 4; ++i) {
            const int kc = wave * 128 + i * 32;
            bf16x8 Ah[4], Al[4], Bh[4], Bl[4];
            #pragma unroll
            for (int rs = 0; rs < 4; ++rs) {
                size_t off = (size_t)(rbase + rs * 16 + lrow) * H_ + kc + quad * 8;
                Ah[rs] = load_h16(ih_hi + off);
                Al[rs] = load_h16(ih_lo + off);
            }
            #pragma unroll
            for (int cs = 0; cs < 4; ++cs) {
                size_t off = (size_t)(cbase + cs * 16 + lrow) * K_ + kc + quad * 8;
                Bh[cs] = *(const bf16x8*)(Whi + off);
                Bl[cs] = *(const bf16x8*)(Wlo + off);
            }
            #pragma unroll
            for (int rs = 0; rs < 4; ++rs)
                #pragma unroll
                for (int cs = 0; cs < 4; ++cs) {
                    acc[rs][cs] = __builtin_amdgcn_mfma_f32_16x16x32_bf16(Ah[rs], Bh[cs], acc[rs][cs], 0, 0, 0);
                    acc[rs][cs] = __builtin_amdgcn_mfma_f32_16x16x32_bf16(Ah[rs], Bl[cs], acc[rs][cs], 0, 0, 0);
                    acc[rs][cs] = __builtin_amdgcn_mfma_f32_16x16x32_bf16(Al[rs], Bh[cs], acc[rs][cs], 0, 0, 0);
                }
        }

        // ---- input part: 1 chunk of 32 from x_t (fp32, split on the fly) ----
        {
            const int kx = wave * 32;            // column within x row slice
            const int kg = 1024 + kx;            // packed-K coordinate
            bf16x8 Ah[4], Al[4], Bh[4], Bl[4];
            #pragma unroll
            for (int rs = 0; rs < 4; ++rs) {
                const float* p = x + (size_t)(rbase + rs * 16 + lrow) * (T_ * D_)
                                   + (size_t)t * D_ + kx + quad * 8;
                float4 v0 = *(const float4*)p;
                float4 v1 = *(const float4*)(p + 4);
                float vv[8] = {v0.x, v0.y, v0.z, v0.w, v1.x, v1.y, v1.z, v1.w};
                bf16x8 h8, l8;
                #pragma unroll
                for (int j = 0; j < 8; ++j) {
                    unsigned short hh, ll;
                    rsplit(vv[j], hh, ll);
                    h8[j] = (short)hh; l8[j] = (short)ll;
                }
                Ah[rs] = h8; Al[rs] = l8;
            }
            #pragma unroll
            for (int cs = 0; cs < 4; ++cs) {
                size_t off = (size_t)(cbase + cs * 16 + lrow) * K_ + kg + quad * 8;
                Bh[cs] = *(const bf16x8*)(Whi + off);
                Bl[cs] = *(const bf16x8*)(Wlo + off);
            }
            #pragma unroll
            for (int rs = 0; rs < 4; ++rs)
                #pragma unroll
                for (int cs = 0; cs < 4; ++cs) {
                    acc[rs][cs] = __builtin_amdgcn_mfma_f32_16x16x32_bf16(Ah[rs], Bh[cs], acc[rs][cs], 0, 0, 0);
                    acc[rs][cs] = __builtin_amdgcn_mfma_f32_16x16x32_bf16(Ah[rs], Bl[cs], acc[rs][cs], 0, 0, 0);
                    acc[rs][cs] = __builtin_amdgcn_mfma_f32_16x16x32_bf16(Al[rs], Bh[cs], acc[rs][cs], 0, 0, 0);
                }
        }

        // ---- per-wave partials -> LDS, [row][col] scalar (2-way max = free) ----
        #pragma unroll
        for (int rs = 0; rs < 4; ++rs)
            #pragma unroll
            for (int cs = 0; cs < 4; ++cs)
                #pragma unroll
                for (int r = 0; r < 4; ++r)
                    zbuf[wave][rs * 16 + quad * 4 + r][cs * 16 + lrow] = acc[rs][cs][r];
        __syncthreads();

        // ---- epilogue: 2 cells per thread; float4 reduce over 8 waves ----
        float zz[8];
        #pragma unroll
        for (int q = 0; q < 2; ++q) {
            float sx = 0.f, sy = 0.f, sz = 0.f, sw = 0.f;
            #pragma unroll
            for (int w = 0; w < 8; ++w) {
                float4 v = *(const float4*)&zbuf[w][b_loc][ce * 8 + q * 4];
                sx += v.x; sy += v.y; sz += v.z; sw += v.w;
            }
            zz[q * 4 + 0] = sx; zz[q * 4 + 1] = sy;
            zz[q * 4 + 2] = sz; zz[q * 4 + 3] = sw;
        }

        unsigned short hh2[2], hl2[2];
        #pragma unroll
        for (int j = 0; j < 2; ++j) {
            float zg = zz[4 * j + 0] + bias[4 * j + 0];
            float zi = zz[4 * j + 1] + bias[4 * j + 1];
            float zf = zz[4 * j + 2] + bias[4 * j + 2];
            float zo = zz[4 * j + 3] + bias[4 * j + 3];
            float g  = tanhf(zg);
            float ig = 1.f / (1.f + expf(-zi));
            float fg = 1.f / (1.f + expf(-zf));
            float og = 1.f / (1.f + expf(-zo));
            float cn = g * ig + creg[j] * fg;
            float hn = tanhf(cn) * og;
            creg[j] = cn;
            rsplit(hn, hh2[j], hl2[j]);
        }
        store_h4(&oh_hi[(size_t)brow * H_ + jg0], hh2[0], hh2[1]);
        store_h4(&oh_lo[(size_t)brow * H_ + jg0], hl2[0], hl2[1]);

        // ---- grid barrier: release-RMW (writeback only), relaxed spin.
        //      NO acquire fence -> per-XCD L2 is never invalidated; h
        //      coherence is carried by the agent-scope atomics themselves.
        __syncthreads();                 // drains vmcnt incl. h atomic stores
        if (tid == 0) {
            __hip_atomic_fetch_add(bar, 1u, __ATOMIC_RELEASE, __HIP_MEMORY_SCOPE_AGENT);
            const unsigned target = (unsigned)NBLK * (unsigned)(t + 1);
            while (__hip_atomic_load(bar, __ATOMIC_RELAXED, __HIP_MEMORY_SCOPE_AGENT) < target)
                __builtin_amdgcn_s_sleep(2);
        }
        __syncthreads();
    }
}

// ---------------------------------------------------------------------------
// Final projection + softmax: one block per batch row, 128 threads.
// ---------------------------------------------------------------------------
__global__ __launch_bounds__(128) void final_proj(
    const unsigned short* __restrict__ hhi, const unsigned short* __restrict__ hlo,
    const float* __restrict__ Why, const float* __restrict__ bhy,
    float* __restrict__ out)
{
    __shared__ float hsh[H_];
    __shared__ float red[O_];
    const int b = blockIdx.x, tid = threadIdx.x;

    for (int k = tid; k < H_; k += O_)
        hsh[k] = bf2f(hhi[(size_t)b * H_ + k]) + bf2f(hlo[(size_t)b * H_ + k]);
    __syncthreads();

    float s = bhy[tid];
    const float* w = Why + (size_t)tid * H_;
    #pragma unroll 4
    for (int k = 0; k < H_; k += 4) {
        float4 wv = *(const float4*)(w + k);
        s += hsh[k] * wv.x + hsh[k + 1] * wv.y + hsh[k + 2] * wv.z + hsh[k + 3] * wv.w;
    }

    red[tid] = s; __syncthreads();
    for (int off = 64; off > 0; off >>= 1) {
        if (tid < off) red[tid] = fmaxf(red[tid], red[tid + off]);
        __syncthreads();
    }
    float mx = red[0]; __syncthreads();
    float e = expf(s - mx);
    red[tid] = e; __syncthreads();
    for (int off = 64; off > 0; off >>= 1) {
        if (tid < off) red[tid] += red[tid + off];
        __syncthreads();
    }
    out[(size_t)b * O_ + tid] = e / red[0];
}

// ---------------------------------------------------------------------------
extern "C" void kernel_launch(void* const* d_in, const int* in_sizes, int n_in,
                              void* d_out, int out_size, void* d_ws, size_t ws_size,
                              hipStream_t stream)
{
    const float* x   = (const float*)d_in[0];
    const float* Wgx = (const float*)d_in[1];
    const float* bgx = (const float*)d_in[2];
    const float* Wgh = (const float*)d_in[3];
    const float* Wix = (const float*)d_in[4];
    const float* bix = (const float*)d_in[5];
    const float* Wih = (const float*)d_in[6];
    const float* Wfx = (const float*)d_in[7];
    const float* bfx = (const float*)d_in[8];
    const float* Wfh = (const float*)d_in[9];
    const float* Wox = (const float*)d_in[10];
    const float* box = (const float*)d_in[11];
    const float* Woh = (const float*)d_in[12];
    const float* Why = (const float*)d_in[13];
    const float* bhy = (const float*)d_in[14];

    // workspace layout (~23 MB)
    unsigned short* Whi   = (unsigned short*)d_ws;
    unsigned short* Wlo   = Whi + (size_t)N4H * K_;
    float*          bP    = (float*)(Wlo + (size_t)N4H * K_);
    unsigned short* hA_hi = (unsigned short*)(bP + N4H);
    unsigned short* hA_lo = hA_hi + (size_t)B_ * H_;
    unsigned short* hB_hi = hA_lo + (size_t)B_ * H_;
    unsigned short* hB_lo = hB_hi + (size_t)B_ * H_;
    unsigned int*   bar   = (unsigned int*)(hB_lo + (size_t)B_ * H_);

    // zero the t=0 read buffer (hA_hi + hA_lo are contiguous) and the barrier
    hipMemsetAsync(hA_hi, 0, (size_t)B_ * H_ * 4, stream);
    hipMemsetAsync(bar, 0, sizeof(unsigned int), stream);

    const int totalW = N4H * K_;
    pack_weights<<<(totalW + 255) / 256, 256, 0, stream>>>(
        Wgx, bgx, Wgh, Wix, bix, Wih, Wfx, bfx, Wfh, Wox, box, Woh,
        Whi, Wlo, bP);

    lstm_persistent<<<NBLK, 512, 0, stream>>>(
        x, Whi, Wlo, bP, hA_hi, hA_lo, hB_hi, hB_lo, bar);

    // t=511 (odd) wrote the A buffers
    final_proj<<<B_, 128, 0, stream>>>(hA_hi, hA_lo, Why, bhy, (float*)d_out);
}